// Round 1
// baseline (1107.973 us; speedup 1.0000x reference)
//
#include <hip/hip_runtime.h>
#include <math.h>

// Sinkhorn loss, B=8, S=2048, P=1024, D=2, eps=0.01, 50 iters.
// Scaled potentials: F = f/eps, G = g/eps.
//   F = -log(S) - LSE_p( -100*C(s,p) + G[p] )
//   G = log_b   - LSE_s( -100*C(s,p) + F[s] )
// dist = sum exp(-100*C + F + G) * C ; out = mean over batch.
// Packs: float4(c0, c1, sqnorm, potential) -> one 16B coalesced load/element.

#define BB 8
#define SS 2048
#define PP 1024
#define NEG_INF -1e9f
#define LOG_S 7.6246189861594f /* log(2048) */
#define ITERS 50

// ws layout (bytes):
//   ypackG : [0,       131072)  B*P float4  (y0,y1,y2, G)
//   xpackF : [131072,  393216)  B*S float4  (x0,x1,x2, F)
//   logb   : [393216,  425984)  B*P float
//   rowsum : [425984,  491520)  B*S float

__global__ __launch_bounds__(1024) void setup_kernel(
    const int* __restrict__ labels, const float* __restrict__ pos,
    float4* __restrict__ ypackG, float* __restrict__ logb) {
  __shared__ int cnt[PP];
  int b = blockIdx.x;
  int t = threadIdx.x;  // 1024 threads
  cnt[t] = 0;
  __syncthreads();
  atomicAdd(&cnt[labels[b * SS + t] & (PP - 1)], 1);
  atomicAdd(&cnt[labels[b * SS + PP + t] & (PP - 1)], 1);
  __syncthreads();
  int c = cnt[t];
  logb[b * PP + t] = (c > 0) ? __logf((float)c * (1.0f / (float)SS)) : NEG_INF;
  float y0 = pos[(b * PP + t) * 2 + 0];
  float y1 = pos[(b * PP + t) * 2 + 1];
  ypackG[b * PP + t] = make_float4(y0, y1, y0 * y0 + y1 * y1, 0.0f);
}

// one wave per (b,s) row; 16 p-elements per lane.
__global__ __launch_bounds__(256) void f_update(
    const float4* __restrict__ ypackG, const float* __restrict__ preds,
    float4* __restrict__ xpackF) {
  int wid = (blockIdx.x << 2) + (threadIdx.x >> 6);  // row id = b*S+s
  int lane = threadIdx.x & 63;
  int b = wid >> 11;
  const float4* yp = ypackG + (b << 10);
  float x0 = preds[(wid << 1) + 0];
  float x1 = preds[(wid << 1) + 1];
  float x2 = x0 * x0 + x1 * x1;
  float v[16];
  float m = -3.4e38f;
#pragma unroll
  for (int i = 0; i < 16; ++i) {
    float4 y = yp[(i << 6) + lane];
    float t = fmaf(x1, y.y, x0 * y.x);
    float c = fmaxf(fmaf(-2.0f, t, x2 + y.z), 0.0f);
    float vv = fmaf(-100.0f, c, y.w);
    v[i] = vv;
    m = fmaxf(m, vv);
  }
#pragma unroll
  for (int off = 32; off; off >>= 1) m = fmaxf(m, __shfl_xor(m, off, 64));
  float sum = 0.0f;
#pragma unroll
  for (int i = 0; i < 16; ++i) sum += __expf(v[i] - m);
#pragma unroll
  for (int off = 32; off; off >>= 1) sum += __shfl_xor(sum, off, 64);
  if (lane == 0) {
    float F = -LOG_S - (m + __logf(sum));
    xpackF[wid] = make_float4(x0, x1, x2, F);
  }
}

// one wave per (b,p) column; 32 s-elements per lane.
__global__ __launch_bounds__(256) void g_update(
    const float4* __restrict__ xpackF, const float* __restrict__ pos,
    const float* __restrict__ logb, float4* __restrict__ ypackG) {
  int wid = (blockIdx.x << 2) + (threadIdx.x >> 6);  // col id = b*P+p
  int lane = threadIdx.x & 63;
  int b = wid >> 10;
  const float4* xp = xpackF + (b << 11);
  float y0 = pos[(wid << 1) + 0];
  float y1 = pos[(wid << 1) + 1];
  float y2 = y0 * y0 + y1 * y1;
  float v[32];
  float m = -3.4e38f;
#pragma unroll
  for (int i = 0; i < 32; ++i) {
    float4 x = xp[(i << 6) + lane];
    float t = fmaf(y1, x.y, y0 * x.x);
    float c = fmaxf(fmaf(-2.0f, t, y2 + x.z), 0.0f);
    float vv = fmaf(-100.0f, c, x.w);
    v[i] = vv;
    m = fmaxf(m, vv);
  }
#pragma unroll
  for (int off = 32; off; off >>= 1) m = fmaxf(m, __shfl_xor(m, off, 64));
  float sum = 0.0f;
#pragma unroll
  for (int i = 0; i < 32; ++i) sum += __expf(v[i] - m);
#pragma unroll
  for (int off = 32; off; off >>= 1) sum += __shfl_xor(sum, off, 64);
  if (lane == 0) {
    float G = logb[wid] - (m + __logf(sum));
    ypackG[wid] = make_float4(y0, y1, y2, G);
  }
}

// one wave per (b,s) row: rowsum[row] = sum_p exp(-100C + F + G) * C
__global__ __launch_bounds__(256) void final_rows(
    const float4* __restrict__ ypackG, const float4* __restrict__ xpackF,
    float* __restrict__ rowsum) {
  int wid = (blockIdx.x << 2) + (threadIdx.x >> 6);
  int lane = threadIdx.x & 63;
  int b = wid >> 11;
  float4 x = xpackF[wid];  // broadcast load (all lanes same addr)
  const float4* yp = ypackG + (b << 10);
  float fg = x.w;  // F; add G per element
  float sum = 0.0f;
#pragma unroll
  for (int i = 0; i < 16; ++i) {
    float4 y = yp[(i << 6) + lane];
    float t = fmaf(x.y, y.y, x.x * y.x);
    float c = fmaxf(fmaf(-2.0f, t, x.z + y.z), 0.0f);
    float v = fmaf(-100.0f, c, fg + y.w);
    sum += __expf(v) * c;
  }
#pragma unroll
  for (int off = 32; off; off >>= 1) sum += __shfl_xor(sum, off, 64);
  if (lane == 0) rowsum[wid] = sum;
}

__global__ __launch_bounds__(1024) void reduce_out(
    const float* __restrict__ rowsum, float* __restrict__ out) {
  __shared__ float sdata[1024];
  int t = threadIdx.x;
  float s = 0.0f;
  for (int i = t; i < BB * SS; i += 1024) s += rowsum[i];
  sdata[t] = s;
  __syncthreads();
  for (int k = 512; k; k >>= 1) {
    if (t < k) sdata[t] += sdata[t + k];
    __syncthreads();
  }
  if (t == 0) out[0] = sdata[0] * (1.0f / (float)BB);
}

extern "C" void kernel_launch(void* const* d_in, const int* in_sizes, int n_in,
                              void* d_out, int out_size, void* d_ws, size_t ws_size,
                              hipStream_t stream) {
  const float* preds = (const float*)d_in[0];   // [B,S,2]
  const int* labels = (const int*)d_in[1];      // [B,S]
  const float* pos = (const float*)d_in[2];     // [B,P,2]
  float* out = (float*)d_out;
  char* ws = (char*)d_ws;
  float4* ypackG = (float4*)(ws);
  float4* xpackF = (float4*)(ws + 131072);
  float* logb = (float*)(ws + 393216);
  float* rowsum = (float*)(ws + 425984);

  hipLaunchKernelGGL(setup_kernel, dim3(BB), dim3(1024), 0, stream,
                     labels, pos, ypackG, logb);
  for (int it = 0; it < ITERS; ++it) {
    hipLaunchKernelGGL(f_update, dim3(BB * SS / 4), dim3(256), 0, stream,
                       ypackG, preds, xpackF);
    hipLaunchKernelGGL(g_update, dim3(BB * PP / 4), dim3(256), 0, stream,
                       xpackF, pos, logb, ypackG);
  }
  hipLaunchKernelGGL(final_rows, dim3(BB * SS / 4), dim3(256), 0, stream,
                     ypackG, xpackF, rowsum);
  hipLaunchKernelGGL(reduce_out, dim3(1), dim3(1024), 0, stream, rowsum, out);
}

// Round 2
// 844.818 us; speedup vs baseline: 1.3115x; 1.3115x over previous
//
#include <hip/hip_runtime.h>
#include <math.h>

// Sinkhorn loss, B=8, S=2048, P=1024, D=2, eps=0.01, 50 iters.
// Base-2 scaled potentials: F2 = f/(eps*ln2), G2 = g/(eps*ln2).
//   v2(s,p) = -K*C(s,p) + G2[p],  K = 100*log2(e)
//   F2 = -log2(S) - LSE2_p(v2);  G2 = logb2 - LSE2_s(-K*C + F2)
// Expansion: -K*C + G2 = (-K*x2) + (2K*x.y) + (G2 - K*y2)
//   row-const ax folds out of LSE; q = G2 - K*y2 precomputed at staging.
// Inner loop: 2 fma + max (pass1), sub + v_exp + add (pass2), u[] in regs.

#define BB 8
#define SS 2048
#define PP 1024
#define NEG_INF -1e9f
#define LOG2S 11.0f
#define ITERS 50
#define K2E 144.269504088896f   /* 100*log2(e) */
#define TWOK 288.539008177792f  /* 200*log2(e) */

__device__ __forceinline__ float fexp2(float x) {
#if __has_builtin(__builtin_amdgcn_exp2f)
  return __builtin_amdgcn_exp2f(x);
#else
  return exp2f(x);
#endif
}
__device__ __forceinline__ float flog2(float x) {
#if __has_builtin(__builtin_amdgcn_logf)
  return __builtin_amdgcn_logf(x);
#else
  return log2f(x);
#endif
}

// ws layout (bytes):
//   ypackG : [0,       131072)  B*P float4  (y0,y1,y2, G2)
//   xpackF : [131072,  393216)  B*S float4  (x0,x1,x2, F2)
//   logb2  : [393216,  425984)  B*P float
//   rowsum : [425984,  491520)  B*S float

__global__ __launch_bounds__(1024) void setup_kernel(
    const int* __restrict__ labels, const float* __restrict__ pos,
    float4* __restrict__ ypackG, float* __restrict__ logb2) {
  __shared__ int cnt[PP];
  int b = blockIdx.x;
  int t = threadIdx.x;  // 1024 threads
  cnt[t] = 0;
  __syncthreads();
  atomicAdd(&cnt[labels[b * SS + t] & (PP - 1)], 1);
  atomicAdd(&cnt[labels[b * SS + PP + t] & (PP - 1)], 1);
  __syncthreads();
  int c = cnt[t];
  logb2[b * PP + t] = (c > 0) ? (flog2((float)c) - LOG2S) : NEG_INF;
  float y0 = pos[(b * PP + t) * 2 + 0];
  float y1 = pos[(b * PP + t) * 2 + 1];
  ypackG[b * PP + t] = make_float4(y0, y1, y0 * y0 + y1 * y1, 0.0f);
}

// f-pass: 512 blocks x 256 thr; block = 32 rows; wave = 8 rows x 8 chunks,
// 128 cols/lane. LDS stages the 1024-entry y-slice (+16B pad per 128).
__global__ __launch_bounds__(256, 2) void f_update(
    const float4* __restrict__ ypackG, const float* __restrict__ preds,
    float4* __restrict__ xpackF) {
  __shared__ float4 sh[1032];
  int t = threadIdx.x;
  int bb = blockIdx.x >> 6;  // 64 blocks per batch
  const float4* ysrc = ypackG + (bb << 10);
#pragma unroll
  for (int k = 0; k < 4; ++k) {
    int e = t + (k << 8);
    float4 y = ysrc[e];
    sh[e + (e >> 7)] = make_float4(y.x, y.y, fmaf(-K2E, y.z, y.w), 0.0f);
  }
  __syncthreads();
  int w = t >> 6, lane = t & 63;
  int r = lane & 7, chunk = lane >> 3;
  int row = (blockIdx.x << 5) + (w << 3) + r;
  const float2* preds2 = (const float2*)preds;
  float2 x = preds2[row];
  float x2 = x.x * x.x + x.y * x.y;
  float kx0 = TWOK * x.x, kx1 = TWOK * x.y;
  const float4* cb = sh + chunk * 129;
  float u[128];
  float m0 = -3.4e38f, m1 = m0, m2 = m0, m3 = m0;
#pragma unroll
  for (int i = 0; i < 128; i += 4) {
    float4 a0 = cb[i], a1 = cb[i + 1], a2 = cb[i + 2], a3 = cb[i + 3];
    float u0 = fmaf(kx0, a0.x, fmaf(kx1, a0.y, a0.z));
    float u1 = fmaf(kx0, a1.x, fmaf(kx1, a1.y, a1.z));
    float u2 = fmaf(kx0, a2.x, fmaf(kx1, a2.y, a2.z));
    float u3 = fmaf(kx0, a3.x, fmaf(kx1, a3.y, a3.z));
    u[i] = u0; u[i + 1] = u1; u[i + 2] = u2; u[i + 3] = u3;
    m0 = fmaxf(m0, u0); m1 = fmaxf(m1, u1);
    m2 = fmaxf(m2, u2); m3 = fmaxf(m3, u3);
  }
  float m = fmaxf(fmaxf(m0, m1), fmaxf(m2, m3));
  m = fmaxf(m, __shfl_xor(m, 8, 64));
  m = fmaxf(m, __shfl_xor(m, 16, 64));
  m = fmaxf(m, __shfl_xor(m, 32, 64));
  float s0 = 0.0f, s1 = 0.0f, s2 = 0.0f, s3 = 0.0f;
#pragma unroll
  for (int i = 0; i < 128; i += 4) {
    s0 += fexp2(u[i] - m);
    s1 += fexp2(u[i + 1] - m);
    s2 += fexp2(u[i + 2] - m);
    s3 += fexp2(u[i + 3] - m);
  }
  float s = (s0 + s1) + (s2 + s3);
  s += __shfl_xor(s, 8, 64);
  s += __shfl_xor(s, 16, 64);
  s += __shfl_xor(s, 32, 64);
  if (lane < 8) {
    // F2 = -log2(S) - (ax + m + log2(s)),  ax = -K*x2
    float F2 = fmaf(K2E, x2, -LOG2S) - m - flog2(s);
    xpackF[row] = make_float4(x.x, x.y, x2, F2);
  }
}

// g-pass: 512 blocks x 256 thr; block = 16 cols; wave = 4 cols x 16 chunks,
// 128 rows/lane. LDS stages the 2048-entry x-slice (+16B pad per 128).
__global__ __launch_bounds__(256, 2) void g_update(
    const float4* __restrict__ xpackF, const float* __restrict__ pos,
    const float* __restrict__ logb2, float4* __restrict__ ypackG) {
  __shared__ float4 sh[2064];
  int t = threadIdx.x;
  int bb = blockIdx.x >> 6;  // 64 blocks per batch
  const float4* xsrc = xpackF + (bb << 11);
#pragma unroll
  for (int k = 0; k < 8; ++k) {
    int e = t + (k << 8);
    float4 x = xsrc[e];
    sh[e + (e >> 7)] = make_float4(x.x, x.y, fmaf(-K2E, x.z, x.w), 0.0f);
  }
  __syncthreads();
  int w = t >> 6, lane = t & 63;
  int r = lane & 3, chunk = lane >> 2;
  int col = (blockIdx.x << 4) + (w << 2) + r;
  const float2* pos2 = (const float2*)pos;
  float2 y = pos2[col];
  float y2 = y.x * y.x + y.y * y.y;
  float ky0 = TWOK * y.x, ky1 = TWOK * y.y;
  const float4* cb = sh + chunk * 129;
  float u[128];
  float m0 = -3.4e38f, m1 = m0, m2 = m0, m3 = m0;
#pragma unroll
  for (int i = 0; i < 128; i += 4) {
    float4 a0 = cb[i], a1 = cb[i + 1], a2 = cb[i + 2], a3 = cb[i + 3];
    float u0 = fmaf(ky0, a0.x, fmaf(ky1, a0.y, a0.z));
    float u1 = fmaf(ky0, a1.x, fmaf(ky1, a1.y, a1.z));
    float u2 = fmaf(ky0, a2.x, fmaf(ky1, a2.y, a2.z));
    float u3 = fmaf(ky0, a3.x, fmaf(ky1, a3.y, a3.z));
    u[i] = u0; u[i + 1] = u1; u[i + 2] = u2; u[i + 3] = u3;
    m0 = fmaxf(m0, u0); m1 = fmaxf(m1, u1);
    m2 = fmaxf(m2, u2); m3 = fmaxf(m3, u3);
  }
  float m = fmaxf(fmaxf(m0, m1), fmaxf(m2, m3));
  m = fmaxf(m, __shfl_xor(m, 4, 64));
  m = fmaxf(m, __shfl_xor(m, 8, 64));
  m = fmaxf(m, __shfl_xor(m, 16, 64));
  m = fmaxf(m, __shfl_xor(m, 32, 64));
  float s0 = 0.0f, s1 = 0.0f, s2 = 0.0f, s3 = 0.0f;
#pragma unroll
  for (int i = 0; i < 128; i += 4) {
    s0 += fexp2(u[i] - m);
    s1 += fexp2(u[i + 1] - m);
    s2 += fexp2(u[i + 2] - m);
    s3 += fexp2(u[i + 3] - m);
  }
  float s = (s0 + s1) + (s2 + s3);
  s += __shfl_xor(s, 4, 64);
  s += __shfl_xor(s, 8, 64);
  s += __shfl_xor(s, 16, 64);
  s += __shfl_xor(s, 32, 64);
  if (lane < 4) {
    // G2 = logb2 - (ay + m + log2(s)),  ay = -K*y2
    float G2 = fmaf(K2E, y2, logb2[col]) - m - flog2(s);
    ypackG[col] = make_float4(y.x, y.y, y2, G2);
  }
}

// one wave per (b,s) row: rowsum[row] = sum_p exp2(-K*C + F2 + G2) * C
__global__ __launch_bounds__(256) void final_rows(
    const float4* __restrict__ ypackG, const float4* __restrict__ xpackF,
    float* __restrict__ rowsum) {
  int wid = (blockIdx.x << 2) + (threadIdx.x >> 6);
  int lane = threadIdx.x & 63;
  int b = wid >> 11;
  float4 x = xpackF[wid];  // broadcast load
  const float4* yp = ypackG + (b << 10);
  float sum = 0.0f;
#pragma unroll
  for (int i = 0; i < 16; ++i) {
    float4 y = yp[(i << 6) + lane];
    float t = fmaf(x.y, y.y, x.x * y.x);
    float c = fmaxf(fmaf(-2.0f, t, x.z + y.z), 0.0f);
    float v2 = fmaf(-K2E, c, x.w + y.w);  // -K*C + F2 + G2 (base-2)
    sum = fmaf(fexp2(v2), c, sum);
  }
#pragma unroll
  for (int off = 32; off; off >>= 1) sum += __shfl_xor(sum, off, 64);
  if (lane == 0) rowsum[wid] = sum;
}

__global__ __launch_bounds__(1024) void reduce_out(
    const float* __restrict__ rowsum, float* __restrict__ out) {
  __shared__ float sdata[1024];
  int t = threadIdx.x;
  float s = 0.0f;
  for (int i = t; i < BB * SS; i += 1024) s += rowsum[i];
  sdata[t] = s;
  __syncthreads();
  for (int k = 512; k; k >>= 1) {
    if (t < k) sdata[t] += sdata[t + k];
    __syncthreads();
  }
  if (t == 0) out[0] = sdata[0] * (1.0f / (float)BB);
}

extern "C" void kernel_launch(void* const* d_in, const int* in_sizes, int n_in,
                              void* d_out, int out_size, void* d_ws, size_t ws_size,
                              hipStream_t stream) {
  const float* preds = (const float*)d_in[0];   // [B,S,2]
  const int* labels = (const int*)d_in[1];      // [B,S]
  const float* pos = (const float*)d_in[2];     // [B,P,2]
  float* out = (float*)d_out;
  char* ws = (char*)d_ws;
  float4* ypackG = (float4*)(ws);
  float4* xpackF = (float4*)(ws + 131072);
  float* logb2 = (float*)(ws + 393216);
  float* rowsum = (float*)(ws + 425984);

  hipLaunchKernelGGL(setup_kernel, dim3(BB), dim3(1024), 0, stream,
                     labels, pos, ypackG, logb2);
  for (int it = 0; it < ITERS; ++it) {
    hipLaunchKernelGGL(f_update, dim3(512), dim3(256), 0, stream,
                       ypackG, preds, xpackF);
    hipLaunchKernelGGL(g_update, dim3(512), dim3(256), 0, stream,
                       xpackF, pos, logb2, ypackG);
  }
  hipLaunchKernelGGL(final_rows, dim3(BB * SS / 4), dim3(256), 0, stream,
                     ypackG, xpackF, rowsum);
  hipLaunchKernelGGL(reduce_out, dim3(1), dim3(1024), 0, stream, rowsum, out);
}